// Round 2
// baseline (1475.262 us; speedup 1.0000x reference)
//
#include <hip/hip_runtime.h>
#include <math.h>

// Problem constants
#define MROWS 2048      // BN*SN = 32*64
#define NCOLS 256       // NDF
#define KDIM  65536     // IN_DIM
#define NCLU  100

// ---- GEMM config ----
#define BM 128
#define BN 128
#define BK 32
#define SPLITK 16
#define KCHUNK (KDIM / SPLITK)   // 4096
#define SA 132   // padded LDS stride for As[k][m]
#define SB 128   // Bs[k][n] stride

// z = z_roi @ w_emb, split-K partial accumulation via global fp32 atomics into C
// (C = z_all region of d_out, pre-zeroed). Bias added in epilogue kernel.
__global__ __launch_bounds__(256, 2)
void gemm_splitk_kernel(const float* __restrict__ A, const float* __restrict__ B,
                        float* __restrict__ C)
{
    __shared__ float As[BK][SA];   // transposed tile: As[k][m]
    __shared__ float Bs[BK][SB];   // Bs[k][n]

    const int t  = threadIdx.x;
    const int tx = t & 15;   // n-group
    const int ty = t >> 4;   // m-group

    const int bm = blockIdx.x;   // 16 m-tiles
    const int bn = blockIdx.y;   // 2  n-tiles
    const int bs = blockIdx.z;   // 16 k-splits

    const float* Ab = A + (size_t)bm * BM * KDIM + (size_t)bs * KCHUNK;
    const float* Bb = B + (size_t)bs * KCHUNK * NCOLS + bn * BN;

    // staging decomposition
    const int arow = t >> 3;   // 0..31  (A tile row, +32 per rep)
    const int akf4 = t & 7;    // 0..7   (A k-float4)
    const int bkr  = t >> 5;   // 0..7   (B tile k-row, +8 per rep)
    const int bnf4 = t & 31;   // 0..31  (B n-float4)

    float acc[8][8];
    #pragma unroll
    for (int i = 0; i < 8; ++i)
        #pragma unroll
        for (int j = 0; j < 8; ++j) acc[i][j] = 0.f;

    for (int kk = 0; kk < KCHUNK; kk += BK) {
        // stage A 128x32 (transpose on LDS write)
        #pragma unroll
        for (int i = 0; i < 4; ++i) {
            const int r = arow + 32 * i;
            const float4 v = *(const float4*)(Ab + (size_t)r * KDIM + kk + akf4 * 4);
            As[akf4 * 4 + 0][r] = v.x;
            As[akf4 * 4 + 1][r] = v.y;
            As[akf4 * 4 + 2][r] = v.z;
            As[akf4 * 4 + 3][r] = v.w;
        }
        // stage B 32x128 (direct layout)
        #pragma unroll
        for (int i = 0; i < 4; ++i) {
            const int r = bkr + 8 * i;
            *(float4*)&Bs[r][bnf4 * 4] =
                *(const float4*)(Bb + (size_t)(kk + r) * NCOLS + bnf4 * 4);
        }
        __syncthreads();

        #pragma unroll 8
        for (int k = 0; k < BK; ++k) {
            float a[8], b[8];
            *(float4*)&a[0] = *(const float4*)&As[k][ty * 4];
            *(float4*)&a[4] = *(const float4*)&As[k][64 + ty * 4];
            *(float4*)&b[0] = *(const float4*)&Bs[k][tx * 4];
            *(float4*)&b[4] = *(const float4*)&Bs[k][64 + tx * 4];
            #pragma unroll
            for (int i = 0; i < 8; ++i)
                #pragma unroll
                for (int j = 0; j < 8; ++j)
                    acc[i][j] = fmaf(a[i], b[j], acc[i][j]);
        }
        __syncthreads();
    }

    // accumulate partials (16 splits per output element)
    #pragma unroll
    for (int i = 0; i < 8; ++i) {
        const int row = bm * BM + ty * 4 + (i & 3) + 64 * (i >> 2);
        #pragma unroll
        for (int j = 0; j < 8; ++j) {
            const int col = bn * BN + tx * 4 + (j & 3) + 64 * (j >> 2);
            atomicAdd(&C[(size_t)row * NCOLS + col], acc[i][j]);
        }
    }
}

// ---- fused bias + mask + student-t + argmax ----
#define RPB 8   // rows per block; grid = 2048/8 = 256 blocks

__global__ __launch_bounds__(256, 1)
void student_t_kernel(float* __restrict__ zbuf,               // [2048,256] raw GEMM sums; becomes z_all in place
                      const int* __restrict__ mask,           // [2048] int32 (numpy bool widened by harness)
                      const float* __restrict__ b_emb,        // [256]
                      const float* __restrict__ cent,         // [100,256]
                      float* __restrict__ s_out,              // [2048,100]
                      float* __restrict__ c_out)              // [2048] argmax as float
{
    // static LDS kept < 64 KB: centroids staged in two 50-row chunks
    __shared__ float cs[50][257];       // stride 257 -> conflict-free cs[k][d] reads
    __shared__ float zs[RPB][256];
    __shared__ float stbuf[RPB][128];   // [_,100..127] zero pad
    __shared__ float c2[NCLU];
    __shared__ float z2s[RPB];
    __shared__ float redbuf[4];
    __shared__ float r_sum, r_idx;

    const int t    = threadIdx.x;
    const int wid  = t >> 6;
    const int lane = t & 63;
    const int row0 = blockIdx.x * RPB;

    const float bt = b_emb[t];

    if (t >= 100 && t < 128) {
        #pragma unroll
        for (int r = 0; r < RPB; ++r) stbuf[r][t] = 0.f;
    }

    // stage z rows: add bias, write z_all back (masked), compute ||z||^2
    for (int r = 0; r < RPB; ++r) {
        const int row = row0 + r;
        const float z = zbuf[(size_t)row * NCOLS + t] + bt;
        const bool m = mask[row] != 0;
        zbuf[(size_t)row * NCOLS + t] = m ? z : 0.f;
        zs[r][t] = z;
        float v = z * z;
        #pragma unroll
        for (int off = 32; off > 0; off >>= 1) v += __shfl_down(v, off, 64);
        if (lane == 0) redbuf[wid] = v;
        __syncthreads();
        if (t == 0) z2s[r] = redbuf[0] + redbuf[1] + redbuf[2] + redbuf[3];
        __syncthreads();
    }

    // two chunks of 50 clusters
    for (int ch = 0; ch < 2; ++ch) {
        const int kbase = ch * 50;
        for (int i = t; i < 50 * 256; i += 256) {
            const int k = i >> 8;
            const int d = i & 255;
            cs[k][d] = cent[(size_t)(kbase + k) * 256 + d];
        }
        __syncthreads();
        if (t < 50) {
            float s = 0.f;
            for (int d = 0; d < 256; ++d) s = fmaf(cs[t][d], cs[t][d], s);
            c2[kbase + t] = s;
        }
        __syncthreads();
        // threads 0..99 handle 2 rows x 50 clusters per pass
        for (int rp = 0; rp < RPB / 2; ++rp) {
            if (t < 100) {
                const int r = rp * 2 + t / 50;
                const int k = t % 50;
                float dot = 0.f;
                for (int d = 0; d < 256; ++d)
                    dot = fmaf(zs[r][d], cs[k][d], dot);
                const float d2   = z2s[r] + c2[kbase + k] - 2.f * dot;
                const float dist = sqrtf(fmaxf(d2, 0.f));
                stbuf[r][kbase + k] = 1.f / (1.f + dist);   // ALPHA=1 -> (1+dist)^-1
            }
        }
        __syncthreads();
    }

    // normalize + argmax per row (wave 0 reduces; first-max-index tiebreak like jnp.argmax)
    for (int r = 0; r < RPB; ++r) {
        const int row = row0 + r;
        if (wid == 0) {
            const float v1 = stbuf[r][lane];
            const float v2 = stbuf[r][lane + 64];
            float sv = v1 + v2;
            #pragma unroll
            for (int off = 32; off > 0; off >>= 1) sv += __shfl_down(sv, off, 64);
            float mv; int mi;
            if (v2 > v1) { mv = v2; mi = lane + 64; } else { mv = v1; mi = lane; }
            #pragma unroll
            for (int off = 32; off > 0; off >>= 1) {
                const float ov = __shfl_down(mv, off, 64);
                const int   oi = __shfl_down(mi, off, 64);
                if (ov > mv || (ov == mv && oi < mi)) { mv = ov; mi = oi; }
            }
            if (lane == 0) { r_sum = sv; r_idx = (float)mi; }
        }
        __syncthreads();
        const bool m = mask[row] != 0;
        if (t < NCLU) s_out[(size_t)row * NCLU + t] = m ? stbuf[r][t] / r_sum : 0.f;
        if (t == 0)   c_out[row] = m ? r_idx : 0.f;
        __syncthreads();
    }
}

extern "C" void kernel_launch(void* const* d_in, const int* in_sizes, int n_in,
                              void* d_out, int out_size, void* d_ws, size_t ws_size,
                              hipStream_t stream)
{
    const float* z_roi = (const float*)d_in[0];
    const int*   mask  = (const int*)d_in[1];   // numpy bool -> int32 per harness convention
    const float* w_emb = (const float*)d_in[2];
    const float* b_emb = (const float*)d_in[3];
    const float* cent  = (const float*)d_in[4];

    float* out   = (float*)d_out;
    float* z_all = out;                                  // 2048*256
    float* s_out = out + (size_t)MROWS * NCOLS;          // 2048*100
    float* c_out = s_out + (size_t)MROWS * NCLU;         // 2048 (as float)

    // zero the split-K accumulator region (d_out is poisoned 0xAA every launch)
    hipMemsetAsync(z_all, 0, (size_t)MROWS * NCOLS * sizeof(float), stream);

    dim3 grid(MROWS / BM, NCOLS / BN, SPLITK);           // 16 x 2 x 16 = 512 blocks
    gemm_splitk_kernel<<<grid, 256, 0, stream>>>(z_roi, w_emb, z_all);

    student_t_kernel<<<dim3(MROWS / RPB), 256, 0, stream>>>(z_all, mask, b_emb, cent,
                                                            s_out, c_out);
}